// Round 3
// baseline (141.368 us; speedup 1.0000x reference)
//
#include <hip/hip_runtime.h>

#define N 512
#define TOPK 153
#define KP 160
#define D 64
#define NB 32          // batches
#define BN (NB*N)
#define EPSF 1e-8f

// ---------------- ws layout (bytes) ----------------
// 0x000000: common f32[N*N]      (1MB)
// 0x100000: G    u64[N*8]        (32KB)  gated selection bitmask (target-major)
// 0x108000: nb   u64[N*8]        (32KB)  symmetrized adjacency + self
// 0x110000: idxl i32[N*KP]       (320KB) top-k source ids per target (rank order)
// 0x160000: wgtl f32[N*KP]       (320KB) raw ew, then normalized weights (in-place)
// 0x1B0000: dinv f32[N]
// 0x1B1000: maxc i32
// 0x1C0000: h    f32[BN*D]       (4MB)

// Fused norms + cosine row + top-k. emb staged TRANSPOSED in LDS so the
// j-indexed reads (lane==j) are consecutive-address -> conflict-free
// (row-major [512][64] would put all 64 lanes in the same bank: 32-way).
__global__ __launch_bounds__(256)
void k_graph(const float* __restrict__ emb, int* __restrict__ idxl,
             unsigned long long* __restrict__ G) {
    __shared__ float esT[D * N];     // 128KB, esT[d*512+j]
    __shared__ float ns[N];
    __shared__ float cr[N];
    __shared__ unsigned long long gb[8];
    int i = blockIdx.x, t = threadIdx.x;
    // stage emb transposed: each thread loads float4 rows, scatters 4 scalars
    for (int e = t; e < N * 16; e += 256) {         // 8192 float4s
        int j = e >> 4, q = e & 15;
        float4 v = ((const float4*)emb)[e];
        esT[(q*4+0)*N + j] = v.x;
        esT[(q*4+1)*N + j] = v.y;
        esT[(q*4+2)*N + j] = v.z;
        esT[(q*4+3)*N + j] = v.w;
    }
    if (t < 8) gb[t] = 0ull;
    __syncthreads();
    // norms (consecutive-lane LDS reads)
    for (int j = t; j < N; j += 256) {
        float s = 0.f;
        #pragma unroll 16
        for (int d = 0; d < D; ++d) { float v = esT[d*N+j]; s = fmaf(v, v, s); }
        ns[j] = sqrtf(s);
    }
    __syncthreads();
    // cosine row i
    float ni = ns[i];
    for (int j = t; j < N; j += 256) {
        float dot = 0.f;
        #pragma unroll 16
        for (int d = 0; d < D; ++d) dot = fmaf(esT[d*N+i], esT[d*N+j], dot);
        cr[j] = dot / (ni*ns[j] + EPSF);
    }
    __syncthreads();
    // exact top-k by rank counting (jax.lax.top_k tie semantics)
    for (int jj = t; jj < N; jj += 256) {
        float v = cr[jj];
        int rank = 0;
        #pragma unroll 8
        for (int m = 0; m < N; ++m) {
            float u = cr[m];
            rank += (u > v) || (u == v && m < jj);
        }
        if (rank < TOPK) {
            idxl[i*KP + rank] = jj;               // rank order == reference order
            atomicOr(&gb[jj>>6], 1ull << (jj&63));
        }
    }
    __syncthreads();
    if (t < 8) G[i*8+t] = gb[t];
}

__global__ void k_nb(const unsigned long long* __restrict__ G,
                     unsigned long long* __restrict__ nbm) {
    int tid = blockIdx.x*256 + threadIdx.x;   // 4096 total
    int a = tid >> 3, w = tid & 7;
    unsigned long long x = G[a*8+w];          // edges where a is target
    int aw = a >> 6, ab = a & 63;
    for (int bit = 0; bit < 64; ++bit) {      // transpose: edges where a is source
        int b = (w<<6) | bit;
        x |= ((G[b*8 + aw] >> ab) & 1ull) << bit;
    }
    if (aw == w) x |= 1ull << ab;             // self loop (nb = adj | I)
    nbm[a*8+w] = x;
}

__global__ void k_common(const unsigned long long* __restrict__ nbm,
                         float* __restrict__ common, int* __restrict__ maxc) {
    __shared__ unsigned long long ni[8];
    __shared__ int bmax;
    int i = blockIdx.x, t = threadIdx.x;
    if (t < 8) ni[t] = nbm[i*8+t];
    if (t == 0) bmax = 0;
    __syncthreads();
    int lm = 0;
    for (int j = t; j < N; j += 256) {
        int c = 0;
        #pragma unroll
        for (int w = 0; w < 8; ++w) c += __popcll(ni[w] & nbm[j*8+w]);
        common[i*N+j] = (float)c;
        lm = lm > c ? lm : c;
    }
    atomicMax(&bmax, lm);
    __syncthreads();
    if (t == 0) atomicMax(maxc, bmax);
}

// per-edge structural coeff + per-node degree, fully parallel
__global__ void k_ew(const float* __restrict__ common, const int* __restrict__ idxl,
                     const int* __restrict__ maxc, float* __restrict__ wgtl,
                     float* __restrict__ dinv) {
    __shared__ float red[4];
    int i = blockIdx.x, k = threadIdx.x;
    float mc = (float)(*maxc);
    float ew = 0.f;
    if (k < TOPK) {
        int j = idxl[i*KP+k];
        float c = common[i*N+j];
        ew = (c > 1.f) ? (c/mc)*c : 0.f;
        wgtl[i*KP+k] = ew;                    // raw ew; scaled in k_wgt2
    }
    float s = ew;
    #pragma unroll
    for (int o = 32; o > 0; o >>= 1) s += __shfl_down(s, o, 64);
    if ((k & 63) == 0) red[k>>6] = s;
    __syncthreads();
    if (k == 0) {
        float deg = red[0]+red[1]+red[2]+red[3];
        dinv[i] = (deg > 0.f) ? (float)(1.0/sqrt((double)deg)) : 0.f;
    }
}

__global__ void k_wgt2(const int* __restrict__ idxl, const float* __restrict__ dinv,
                       float* __restrict__ wgtl) {
    int tid = blockIdx.x*256 + threadIdx.x;   // 512*KP -> grid 320
    int i = tid / KP, k = tid % KP;
    if (k >= TOPK) return;
    int j = idxl[i*KP+k];
    wgtl[i*KP+k] *= dinv[j]*dinv[i];          // dinv[row]*ew*dinv[col]
}

__global__ void k_h(const float* __restrict__ x, const float* __restrict__ W,
                    float* __restrict__ h) {
    __shared__ float xs[16*64];
    __shared__ float Ws[64*64];
    int t = threadIdx.x; int r0 = blockIdx.x*16;
    ((float4*)xs)[t] = ((const float4*)(x + r0*64))[t];
    for (int e = t; e < 1024; e += 256) ((float4*)Ws)[e] = ((const float4*)W)[e];
    __syncthreads();
    int row = t >> 4, f0 = (t & 15)*4;
    float ax=0, ay=0, az=0, aw=0;
    #pragma unroll 8
    for (int c = 0; c < 64; ++c) {
        float xv = xs[row*64+c];
        float4 wv = *(const float4*)&Ws[c*64+f0];
        ax += xv*wv.x; ay += xv*wv.y; az += xv*wv.z; aw += xv*wv.w;
    }
    float4 o; o.x=ax; o.y=ay; o.z=az; o.w=aw;
    ((float4*)(h + r0*64))[t] = o;
}

// v2: index/weight reads moved off the LDS pipe to global (wave-broadcast,
// L2-resident); only h stays LDS-staged. One sync per block.
__global__ __launch_bounds__(512)
void k_agg2(const float* __restrict__ h, const int* __restrict__ idxl,
            const float* __restrict__ wgtl, const float* __restrict__ bias,
            float* __restrict__ out) {
    __shared__ float4 hs4[512*16];   // 128KB: h[b] staged
    int chunk = blockIdx.x, b = blockIdx.y, t = threadIdx.x;
    const float4* hb = (const float4*)h + b*8192;
    for (int e = t; e < 8192; e += 512) hs4[e] = hb[e];
    int lane = t & 63, wv = t >> 6;
    int ts = lane >> 4, fq = lane & 15;
    int tl = wv*4 + ts;              // local target 0..31
    float4 bv = ((const float4*)bias)[fq];
    __syncthreads();
    #pragma unroll
    for (int grp = 0; grp < 2; ++grp) {
        int ti = chunk*64 + grp*32 + tl;
        const int*   ip = &idxl[ti*KP];
        const float* wp = &wgtl[ti*KP];
        float ax=0, ay=0, az=0, aw=0;
        #pragma unroll 4
        for (int kk = 0; kk < TOPK; ++kk) {
            int j = ip[kk];
            float w = wp[kk];
            float4 hv = hs4[j*16 + fq];
            ax += w*hv.x; ay += w*hv.y; az += w*hv.z; aw += w*hv.w;
        }
        float4 o; o.x = ax+bv.x; o.y = ay+bv.y; o.z = az+bv.z; o.w = aw+bv.w;
        ((float4*)out)[(b*512 + ti)*16 + fq] = o;
    }
}

extern "C" void kernel_launch(void* const* d_in, const int* in_sizes, int n_in,
                              void* d_out, int out_size, void* d_ws, size_t ws_size,
                              hipStream_t stream) {
    const float* x    = (const float*)d_in[0];   // [32,512,64]
    const float* W    = (const float*)d_in[1];   // [64,64]
    const float* bias = (const float*)d_in[2];   // [64]
    const float* emb  = (const float*)d_in[3];   // [512,64]
    float* out = (float*)d_out;

    char* ws = (char*)d_ws;
    float* common = (float*)(ws + 0x000000);
    unsigned long long* G   = (unsigned long long*)(ws + 0x100000);
    unsigned long long* nbm = (unsigned long long*)(ws + 0x108000);
    int*   idxl  = (int*)(ws + 0x110000);
    float* wgtl  = (float*)(ws + 0x160000);
    float* dinv  = (float*)(ws + 0x1B0000);
    int*   maxc  = (int*)(ws + 0x1B1000);
    float* h     = (float*)(ws + 0x1C0000);

    hipMemsetAsync(maxc, 0, sizeof(int), stream);
    k_graph<<<N, 256, 0, stream>>>(emb, idxl, G);
    k_nb<<<16, 256, 0, stream>>>(G, nbm);
    k_common<<<N, 256, 0, stream>>>(nbm, common, maxc);
    k_ew<<<N, 256, 0, stream>>>(common, idxl, maxc, wgtl, dinv);
    k_wgt2<<<320, 256, 0, stream>>>(idxl, dinv, wgtl);
    k_h<<<BN/16, 256, 0, stream>>>(x, W, h);
    k_agg2<<<dim3(8, NB), 512, 0, stream>>>(h, idxl, wgtl, bias, out);
}

// Round 4
// 92.174 us; speedup vs baseline: 1.5337x; 1.5337x over previous
//
#include <hip/hip_runtime.h>

#define N 512
#define TOPK 153
#define KP 160
#define D 64
#define NB 32          // batches
#define BN (NB*N)
#define EPSF 1e-8f

// ---------------- ws layout (bytes) ----------------
// 0x100000: G    u64[N*8]        (32KB)  gated selection bitmask (target-major)
// 0x108000: nbm  u64[N*8]        (32KB)  symmetrized adjacency + self
// 0x110000: idxl i32[N*KP]       (320KB) top-k source ids per target (rank order)
// 0x160000: wgtl f32[N*KP]       (320KB) c^2 * rs_i  (row-scaled structural coeff)
// 0x1B0000: rs   f32[N]          1/sqrt(sum_k c_ik^2)   [max_common cancels]
// 0x1C0000: h    f32[BN*D]       (4MB)

// Fused norms + cosine row + exact top-k for one node i per block.
// emb is L2-resident (128KB) -- no giant LDS stage (R3 lesson: 32-way
// write conflicts + 1 block/CU). Per-thread coalesced row reads; dot and
// normsq computed in the same pass. LDS = 4.4KB -> many blocks/CU.
__global__ __launch_bounds__(256)
void k_front(const float* __restrict__ emb, int* __restrict__ idxl,
             unsigned long long* __restrict__ G) {
    __shared__ float cr[N];          // raw dots, then cosine
    __shared__ float q2[N];          // norm^2 per node
    __shared__ float ri[D];          // row i
    __shared__ unsigned long long gb[8];
    int i = blockIdx.x, t = threadIdx.x;
    if (t < 16) ((float4*)ri)[t] = ((const float4*)(emb + i*D))[t];
    if (t < 8) gb[t] = 0ull;
    __syncthreads();
    // dot(i,j) and |j|^2 in one pass over row j (16 float4 per thread)
    for (int j = t; j < N; j += 256) {
        const float4* rj = (const float4*)(emb + j*D);
        float dot = 0.f, nsq = 0.f;
        #pragma unroll
        for (int q = 0; q < 16; ++q) {
            float4 v = rj[q];
            float4 u = ((const float4*)ri)[q];       // LDS broadcast
            dot = fmaf(u.x,v.x,fmaf(u.y,v.y,fmaf(u.z,v.z,fmaf(u.w,v.w,dot))));
            nsq = fmaf(v.x,v.x,fmaf(v.y,v.y,fmaf(v.z,v.z,fmaf(v.w,v.w,nsq))));
        }
        cr[j] = dot; q2[j] = nsq;
    }
    __syncthreads();
    float ni = sqrtf(q2[i]);
    for (int j = t; j < N; j += 256)
        cr[j] = cr[j] / (ni*sqrtf(q2[j]) + EPSF);
    __syncthreads();
    // exact top-k by rank counting (jax.lax.top_k tie semantics)
    for (int jj = t; jj < N; jj += 256) {
        float v = cr[jj];
        int rank = 0;
        #pragma unroll 8
        for (int m = 0; m < N; ++m) {
            float u = cr[m];                          // LDS broadcast
            rank += (u > v) || (u == v && m < jj);
        }
        if (rank < TOPK) {
            idxl[i*KP + rank] = jj;                   // rank order == ref order
            atomicOr(&gb[jj>>6], 1ull << (jj&63));
        }
    }
    __syncthreads();
    if (t < 8) G[i*8+t] = gb[t];
}

// Grid-fused: blocks 0..15 symmetrize adjacency (+self) into bitmasks;
// blocks 16..1039 compute h = x @ W (independent of the graph chain).
__global__ __launch_bounds__(256)
void k_nbh(const unsigned long long* __restrict__ G, unsigned long long* __restrict__ nbm,
           const float* __restrict__ x, const float* __restrict__ W,
           float* __restrict__ h) {
    __shared__ float xs[16*64];
    __shared__ float Ws[64*64];
    int t = threadIdx.x;
    if (blockIdx.x < 16) {
        int tid = blockIdx.x*256 + t;             // 4096 total
        int a = tid >> 3, w = tid & 7;
        unsigned long long v = G[a*8+w];          // edges where a is target
        int aw = a >> 6, ab = a & 63;
        for (int bit = 0; bit < 64; ++bit) {      // transpose: a as source
            int b = (w<<6) | bit;
            v |= ((G[b*8 + aw] >> ab) & 1ull) << bit;
        }
        if (aw == w) v |= 1ull << ab;             // self loop
        nbm[a*8+w] = v;
        return;
    }
    int r0 = (blockIdx.x - 16) * 16;
    ((float4*)xs)[t] = ((const float4*)(x + r0*64))[t];
    for (int e = t; e < 1024; e += 256) ((float4*)Ws)[e] = ((const float4*)W)[e];
    __syncthreads();
    int row = t >> 4, f0 = (t & 15)*4;
    float ax=0, ay=0, az=0, aw=0;
    #pragma unroll 8
    for (int c = 0; c < 64; ++c) {
        float xv = xs[row*64+c];
        float4 wv = *(const float4*)&Ws[c*64+f0];
        ax += xv*wv.x; ay += xv*wv.y; az += xv*wv.z; aw += xv*wv.w;
    }
    float4 o; o.x=ax; o.y=ay; o.z=az; o.w=aw;
    ((float4*)(h + r0*64))[t] = o;
}

// Per-edge common-neighbor count straight from bitmasks (no 1MB common
// matrix, no max_common -- it cancels in the gcn norm). Stores c^2*rs_i.
__global__ __launch_bounds__(256)
void k_edge1(const unsigned long long* __restrict__ nbm, const int* __restrict__ idxl,
             float* __restrict__ wgtl, float* __restrict__ rs) {
    __shared__ unsigned long long ni[8];
    __shared__ float red[4];
    __shared__ float rsb;
    int i = blockIdx.x, k = threadIdx.x;
    if (k < 8) ni[k] = nbm[i*8+k];
    __syncthreads();
    float c2 = 0.f;
    if (k < TOPK) {
        int j = idxl[i*KP+k];
        const ulonglong2* nj = (const ulonglong2*)(nbm + j*8);
        int c = 0;
        #pragma unroll
        for (int w = 0; w < 4; ++w) {
            ulonglong2 v = nj[w];
            c += __popcll(ni[2*w] & v.x) + __popcll(ni[2*w+1] & v.y);
        }
        c2 = (float)(c*c);                 // edge always has c>=2 (self+reverse)
    }
    float s = c2;
    #pragma unroll
    for (int o = 32; o > 0; o >>= 1) s += __shfl_down(s, o, 64);
    if ((k & 63) == 0) red[k>>6] = s;
    __syncthreads();
    if (k == 0) {
        float deg = red[0]+red[1]+red[2]+red[3];   // > 0 always
        rsb = (float)(1.0/sqrt((double)deg));
        rs[i] = rsb;
    }
    __syncthreads();
    if (k < TOPK) wgtl[i*KP+k] = c2 * rsb;
}

// h[b] staged in LDS (conflict-free b128 gather); indices/weights read from
// global (wave-broadcast, L2-hot); final weight = wn[k] * rs[j] on the fly.
__global__ __launch_bounds__(512)
void k_agg3(const float* __restrict__ h, const int* __restrict__ idxl,
            const float* __restrict__ wn, const float* __restrict__ rs,
            const float* __restrict__ bias, float* __restrict__ out) {
    __shared__ float4 hs4[512*16];   // 128KB: h[b] staged
    int chunk = blockIdx.x, b = blockIdx.y, t = threadIdx.x;
    const float4* hb = (const float4*)h + b*8192;
    for (int e = t; e < 8192; e += 512) hs4[e] = hb[e];
    int lane = t & 63, wv = t >> 6;
    int ts = lane >> 4, fq = lane & 15;
    int tl = wv*4 + ts;              // local target 0..31
    float4 bv = ((const float4*)bias)[fq];
    __syncthreads();
    #pragma unroll
    for (int grp = 0; grp < 2; ++grp) {
        int ti = chunk*64 + grp*32 + tl;
        const int*   ip = &idxl[ti*KP];
        const float* wp = &wn[ti*KP];
        float ax=0, ay=0, az=0, aw=0;
        #pragma unroll 4
        for (int kk = 0; kk < TOPK; ++kk) {
            int j = ip[kk];
            float w = wp[kk] * rs[j];
            float4 hv = hs4[j*16 + fq];
            ax += w*hv.x; ay += w*hv.y; az += w*hv.z; aw += w*hv.w;
        }
        float4 o; o.x = ax+bv.x; o.y = ay+bv.y; o.z = az+bv.z; o.w = aw+bv.w;
        ((float4*)out)[(b*512 + ti)*16 + fq] = o;
    }
}

extern "C" void kernel_launch(void* const* d_in, const int* in_sizes, int n_in,
                              void* d_out, int out_size, void* d_ws, size_t ws_size,
                              hipStream_t stream) {
    const float* x    = (const float*)d_in[0];   // [32,512,64]
    const float* W    = (const float*)d_in[1];   // [64,64]
    const float* bias = (const float*)d_in[2];   // [64]
    const float* emb  = (const float*)d_in[3];   // [512,64]
    float* out = (float*)d_out;

    char* ws = (char*)d_ws;
    unsigned long long* G   = (unsigned long long*)(ws + 0x100000);
    unsigned long long* nbm = (unsigned long long*)(ws + 0x108000);
    int*   idxl = (int*)(ws + 0x110000);
    float* wgtl = (float*)(ws + 0x160000);
    float* rs   = (float*)(ws + 0x1B0000);
    float* h    = (float*)(ws + 0x1C0000);

    k_front<<<N, 256, 0, stream>>>(emb, idxl, G);
    k_nbh<<<16 + BN/16, 256, 0, stream>>>(G, nbm, x, W, h);
    k_edge1<<<N, 256, 0, stream>>>(nbm, idxl, wgtl, rs);
    k_agg3<<<dim3(8, NB), 512, 0, stream>>>(h, idxl, wgtl, rs, bias, out);
}